// Round 15
// baseline (153.155 us; speedup 1.0000x reference)
//
#include <hip/hip_runtime.h>
#include <hip/hip_bf16.h>

#define B_DIM 4096
#define M_DIM 4096
#define K_DIM 4096
#define NCODE 512

typedef __attribute__((ext_vector_type(16))) float f32x16;
typedef __attribute__((ext_vector_type(8))) short short8;

__device__ __forceinline__ unsigned short f2bf(float f) {
    union { float f; unsigned u; } c; c.f = f;
    unsigned u = c.u;
    return (unsigned short)((u + 0x7FFFu + ((u >> 16) & 1u)) >> 16);
}

// ---------------------------------------------------------------------------
// Fused prep: blocks [0,8192) dequantize codes -> bf16 W; [8192,16384) cvt A.
// ---------------------------------------------------------------------------
__global__ __launch_bounds__(256) void prep_kernel(const int* __restrict__ Q,
                                                   const float* __restrict__ cb,
                                                   short* __restrict__ Wout,
                                                   const float* __restrict__ in,
                                                   short* __restrict__ Ab) {
    const int b = blockIdx.x;
    if (b < 8192) {
        const int t = b * 256 + threadIdx.x;
        const int code = Q[t] & 0xFFFF;
        const float4* g = (const float4*)(cb + (size_t)code * 8);
        const float4 v0 = g[0];
        const float4 v1 = g[1];
        short8 o;
        o[0] = f2bf(v0.x); o[1] = f2bf(v0.y); o[2] = f2bf(v0.z); o[3] = f2bf(v0.w);
        o[4] = f2bf(v1.x); o[5] = f2bf(v1.y); o[6] = f2bf(v1.z); o[7] = f2bf(v1.w);
        *(short8*)(Wout + (size_t)t * 8) = o;
    } else {
        const int t = (b - 8192) * 256 + threadIdx.x;
        const float4* p = (const float4*)(in + (size_t)t * 8);
        const float4 v0 = p[0];
        const float4 v1 = p[1];
        short8 o;
        o[0] = f2bf(v0.x); o[1] = f2bf(v0.y); o[2] = f2bf(v0.z); o[3] = f2bf(v0.w);
        o[4] = f2bf(v1.x); o[5] = f2bf(v1.y); o[6] = f2bf(v1.z); o[7] = f2bf(v1.w);
        *(short8*)(Ab + (size_t)t * 8) = o;
    }
}

// ---------------------------------------------------------------------------
// GEMM: C[B,M] = A[B,K] * W[M,K]^T — r8/r14 structure (256x256 tile, BK=64,
// 8 waves 2x4 with 128x64 wave tiles, 2-deep ring, 4-phase reg-decoupled
// pipeline, 2 barriers/iter) with MFMA shape = 32x32x16 (µbench 2495 TF vs
// 2075 for 16x16x32). Per iter: 32 MFMA (4m x 2n x 4kk), A-frag reads 16,
// B-frag reads 8 — identical counts to r14.
//   ph0: MFMA (m0-1 x n0-1 x kk0-1) ; read a1=(m2-3,kk0-1) ; 4 A-GLD(t+1)
//   ph1: MFMA (m2-3 x kk0-1)        ; read a2=(m0-1,kk2-3), b2=(n0-1,kk2-3) ;
//        4 B-GLD(t+1)
//   ph2: MFMA (m0-1 x kk2-3)        ; read a3=(m2-3,kk2-3) ; vmcnt(0) ; bar
//   ph3: MFMA (m2-3 x kk2-3)        ; read next-tile aC,bC from bufn ;
//        lgkmcnt(8) ; bar
// Hazard proof identical to r14 (verified, absmax 2.0).
// Frag layout 32x32x16 (validated by r6 pass): A row = lane&31,
// k = (lane>>5)*8 + e; C/D col = lane&31, row = (reg&3)+8*(reg>>2)+4*(lane>>5).
// LDS swizzle: stored unit = u ^ (row&7); rows 32-aligned per subtile so
// row&7 == l31&7; per 16-lane quarter each frag read hits 8 slots x 2 lanes
// (free). GLOBAL source inverse-swizzled (both-sides rule).
// ---------------------------------------------------------------------------
#define BM 256
#define BN 256
#define BK 64
#define NT (K_DIM / BK)   // 64

#define GLD(src, dst) \
    __builtin_amdgcn_global_load_lds( \
        (const __attribute__((address_space(1))) void*)(src), \
        (__attribute__((address_space(3))) void*)(dst), 16, 0, 0)

#define MFMA32(a, b, c) __builtin_amdgcn_mfma_f32_32x32x16_bf16(a, b, c, 0, 0, 0)

__global__ __launch_bounds__(512, 2) void gemm_bt_kernel(const short* __restrict__ A,
                                                         const short* __restrict__ Wd,
                                                         float* __restrict__ C) {
    __shared__ short lds[2 * 32768];   // 2 bufs x (A 32KB | B 32KB) = 128 KB

    const int tid  = threadIdx.x;
    const int wave = tid >> 6;
    const int lane = tid & 63;

    // XCD-chunked swizzle: 256 blocks -> 8 XCDs, each a 4x8 block chunk
    const int bid = blockIdx.x;
    const int xcd = bid & 7;
    const int s   = bid >> 3;
    const int by  = (xcd >> 1) * 4 + (s >> 3);
    const int bx  = (xcd & 1) * 8 + (s & 7);

    const int rowBase = by * BM;
    const int colBase = bx * BN;

    const int wr = wave >> 2;                 // 0..1  (128-row half)
    const int wc = wave & 3;                  // 0..3  (64-col quarter)

    // ---- staging: thread covers rows (tid>>3)+c*64, stored unit tid&7 ----
    const int rA0 = tid >> 3;                 // 0..63
    const int uu  = (tid & 7) ^ (rA0 & 7);    // inverse-swizzled logical unit
    const int stOff = rA0 * 64 + (tid & 7) * 8;   // shorts; +c*4096
    const short* aSrcB = A  + (size_t)(rowBase + rA0) * K_DIM + uu * 8;
    const short* bSrcB = Wd + (size_t)(colBase + rA0) * K_DIM + uu * 8;

    // ---- fragment read offsets (shorts) ----
    const int l31 = lane & 31;
    const int l5  = lane >> 5;                // 0..1
    const int xr  = l31 & 7;
    int uk[4];
#pragma unroll
    for (int kk = 0; kk < 4; ++kk)
        uk[kk] = ((kk * 2 + l5) ^ xr) * 8;    // swizzled 16B-unit offset
    const int aRow = (wr * 128 + l31) * 64;           // + m*2048 + uk[kk]
    const int bRow = 16384 + (wc * 64 + l31) * 64;    // + n*2048 + uk[kk]

    f32x16 acc[4][2] = {};
    // aC = (m0-1, kk0-1), bC = (n0-1, kk0-1): index [i*2+kk]
    short8 aC[4], bC[4];

    // ---- prologue: stage tile 0 into buf0, publish, read ph0 frags ----
#pragma unroll
    for (int c = 0; c < 4; ++c)
        GLD(aSrcB + c * (64 * K_DIM), &lds[c * 4096 + stOff]);
#pragma unroll
    for (int c = 0; c < 4; ++c)
        GLD(bSrcB + c * (64 * K_DIM), &lds[16384 + c * 4096 + stOff]);
    asm volatile("s_waitcnt vmcnt(0)" ::: "memory");
    __builtin_amdgcn_s_barrier();
#pragma unroll
    for (int m = 0; m < 2; ++m)
#pragma unroll
        for (int kk = 0; kk < 2; ++kk)
            aC[m * 2 + kk] = *(const short8*)&lds[aRow + m * 2048 + uk[kk]];
#pragma unroll
    for (int n = 0; n < 2; ++n)
#pragma unroll
        for (int kk = 0; kk < 2; ++kk)
            bC[n * 2 + kk] = *(const short8*)&lds[bRow + n * 2048 + uk[kk]];

    for (int t = 0; t < NT; ++t) {
        const int buf  = (t & 1) * 32768;
        const int bufn = buf ^ 32768;
        const size_t kpre = (size_t)(((t + 1 < NT) ? (t + 1) : (NT - 1)) * BK);

        // ---- ph0: MFMA m0-1 x kk0-1 ; read a1=(m2-3,kk0-1) ; 4 A-GLD ----
        short8 a1[4];
#pragma unroll
        for (int m = 0; m < 2; ++m)
#pragma unroll
            for (int kk = 0; kk < 2; ++kk)
                a1[m * 2 + kk] = *(const short8*)&lds[buf + aRow + (m + 2) * 2048 + uk[kk]];
#pragma unroll
        for (int c = 0; c < 4; ++c)
            GLD(aSrcB + kpre + c * (64 * K_DIM), &lds[bufn + c * 4096 + stOff]);
        __builtin_amdgcn_s_setprio(1);
#pragma unroll
        for (int m = 0; m < 2; ++m)
#pragma unroll
            for (int n = 0; n < 2; ++n)
#pragma unroll
                for (int kk = 0; kk < 2; ++kk)
                    acc[m][n] = MFMA32(aC[m * 2 + kk], bC[n * 2 + kk], acc[m][n]);
        __builtin_amdgcn_s_setprio(0);

        // ---- ph1: MFMA m2-3 x kk0-1 ; read a2=(m0-1,kk2-3), b2 ; 4 B-GLD ----
        short8 a2[4], b2[4];
#pragma unroll
        for (int m = 0; m < 2; ++m)
#pragma unroll
            for (int kk = 0; kk < 2; ++kk)
                a2[m * 2 + kk] = *(const short8*)&lds[buf + aRow + m * 2048 + uk[kk + 2]];
#pragma unroll
        for (int n = 0; n < 2; ++n)
#pragma unroll
            for (int kk = 0; kk < 2; ++kk)
                b2[n * 2 + kk] = *(const short8*)&lds[buf + bRow + n * 2048 + uk[kk + 2]];
#pragma unroll
        for (int c = 0; c < 4; ++c)
            GLD(bSrcB + kpre + c * (64 * K_DIM), &lds[bufn + 16384 + c * 4096 + stOff]);
        __builtin_amdgcn_s_setprio(1);
#pragma unroll
        for (int m = 0; m < 2; ++m)
#pragma unroll
            for (int n = 0; n < 2; ++n)
#pragma unroll
                for (int kk = 0; kk < 2; ++kk)
                    acc[m + 2][n] = MFMA32(a1[m * 2 + kk], bC[n * 2 + kk], acc[m + 2][n]);
        __builtin_amdgcn_s_setprio(0);

        // ---- ph2: MFMA m0-1 x kk2-3 ; read a3=(m2-3,kk2-3) ; vmcnt(0)+bar ----
        short8 a3[4];
#pragma unroll
        for (int m = 0; m < 2; ++m)
#pragma unroll
            for (int kk = 0; kk < 2; ++kk)
                a3[m * 2 + kk] = *(const short8*)&lds[buf + aRow + (m + 2) * 2048 + uk[kk + 2]];
        __builtin_amdgcn_s_setprio(1);
#pragma unroll
        for (int m = 0; m < 2; ++m)
#pragma unroll
            for (int n = 0; n < 2; ++n)
#pragma unroll
                for (int kk = 0; kk < 2; ++kk)
                    acc[m][n] = MFMA32(a2[m * 2 + kk], b2[n * 2 + kk], acc[m][n]);
        __builtin_amdgcn_s_setprio(0);
        asm volatile("s_waitcnt vmcnt(0)" ::: "memory");   // tile t+1 landed
        __builtin_amdgcn_s_barrier();

        // ---- ph3: MFMA m2-3 x kk2-3 ; read next-tile ph0 frags from bufn ----
#pragma unroll
        for (int m = 0; m < 2; ++m)
#pragma unroll
            for (int kk = 0; kk < 2; ++kk)
                aC[m * 2 + kk] = *(const short8*)&lds[bufn + aRow + m * 2048 + uk[kk]];
#pragma unroll
        for (int n = 0; n < 2; ++n)
#pragma unroll
            for (int kk = 0; kk < 2; ++kk)
                bC[n * 2 + kk] = *(const short8*)&lds[bufn + bRow + n * 2048 + uk[kk]];
        __builtin_amdgcn_s_setprio(1);
#pragma unroll
        for (int m = 0; m < 2; ++m)
#pragma unroll
            for (int n = 0; n < 2; ++n)
#pragma unroll
                for (int kk = 0; kk < 2; ++kk)
                    acc[m + 2][n] = MFMA32(a3[m * 2 + kk], b2[n * 2 + kk], acc[m + 2][n]);
        __builtin_amdgcn_s_setprio(0);
        asm volatile("s_waitcnt lgkmcnt(8)" ::: "memory"); // buf(t) reads drained
        __builtin_amdgcn_s_barrier();
    }

    // ---- epilogue: C/D col = lane&31, row = (reg&3)+8*(reg>>2)+4*l5 ----
    const int r0 = rowBase + wr * 128 + 4 * l5;
    const int c0 = colBase + wc * 64 + l31;
#pragma unroll
    for (int ms = 0; ms < 4; ++ms)
#pragma unroll
        for (int ns = 0; ns < 2; ++ns) {
            float* cp = C + (size_t)(r0 + ms * 32) * M_DIM + (c0 + ns * 32);
#pragma unroll
            for (int reg = 0; reg < 16; ++reg) {
                const int rr = (reg & 3) + 8 * (reg >> 2);
                cp[(size_t)rr * M_DIM] = acc[ms][ns][reg];
            }
        }
}

// ---------------------------------------------------------------------------
extern "C" void kernel_launch(void* const* d_in, const int* in_sizes, int n_in,
                              void* d_out, int out_size, void* d_ws, size_t ws_size,
                              hipStream_t stream) {
    const float* inp  = (const float*)d_in[0];
    const int*   qidx = (const int*)d_in[1];
    const float* cb   = (const float*)d_in[2];
    float* out = (float*)d_out;

    short* Wb = (short*)d_ws;
    short* Ab = Wb + (size_t)M_DIM * K_DIM;

    prep_kernel<<<16384, 256, 0, stream>>>(qidx, cb, Wb, inp, Ab);

    gemm_bt_kernel<<<256, 512, 0, stream>>>(Ab, Wb, out);
}

// Round 16
// 133.870 us; speedup vs baseline: 1.1441x; 1.1441x over previous
//
#include <hip/hip_runtime.h>
#include <hip/hip_bf16.h>

#define B_DIM 4096
#define M_DIM 4096
#define K_DIM 4096
#define NCODE 512

typedef __attribute__((ext_vector_type(4))) float f32x4;
typedef __attribute__((ext_vector_type(8))) short short8;

__device__ __forceinline__ unsigned short f2bf(float f) {
    union { float f; unsigned u; } c; c.f = f;
    unsigned u = c.u;
    return (unsigned short)((u + 0x7FFFu + ((u >> 16) & 1u)) >> 16);
}

// ---------------------------------------------------------------------------
// Fused prep: blocks [0,8192) dequantize codes -> bf16 W; [8192,16384) cvt A.
// Memory-bound (~134 MB at effective >6 TB/s incl. L3 absorption) — at BW
// roofline for this pass.
// ---------------------------------------------------------------------------
__global__ __launch_bounds__(256) void prep_kernel(const int* __restrict__ Q,
                                                   const float* __restrict__ cb,
                                                   short* __restrict__ Wout,
                                                   const float* __restrict__ in,
                                                   short* __restrict__ Ab) {
    const int b = blockIdx.x;
    if (b < 8192) {
        const int t = b * 256 + threadIdx.x;
        const int code = Q[t] & 0xFFFF;
        const float4* g = (const float4*)(cb + (size_t)code * 8);
        const float4 v0 = g[0];
        const float4 v1 = g[1];
        short8 o;
        o[0] = f2bf(v0.x); o[1] = f2bf(v0.y); o[2] = f2bf(v0.z); o[3] = f2bf(v0.w);
        o[4] = f2bf(v1.x); o[5] = f2bf(v1.y); o[6] = f2bf(v1.z); o[7] = f2bf(v1.w);
        *(short8*)(Wout + (size_t)t * 8) = o;
    } else {
        const int t = (b - 8192) * 256 + threadIdx.x;
        const float4* p = (const float4*)(in + (size_t)t * 8);
        const float4 v0 = p[0];
        const float4 v1 = p[1];
        short8 o;
        o[0] = f2bf(v0.x); o[1] = f2bf(v0.y); o[2] = f2bf(v0.z); o[3] = f2bf(v0.w);
        o[4] = f2bf(v1.x); o[5] = f2bf(v1.y); o[6] = f2bf(v1.z); o[7] = f2bf(v1.w);
        *(short8*)(Ab + (size_t)t * 8) = o;
    }
}

// ---------------------------------------------------------------------------
// GEMM: C[B,M] = A[B,K] * W[M,K]^T — 256x256 tile, BK=64, 8 waves (2x4, wave
// tile 128x64), 16x16x32 MFMA, 2-deep LDS ring (128 KB), 4-phase register
// pipeline (phase p reads phase p+1's frags), 2 barriers/iter.
//   ph0: MFMA m0-3/h0 (frags from prev ph3/prologue) || read aH0[4-7] || 4 A-GLD(t+1)
//   ph1: MFMA m4-7/h0 || read aH1[0-3], bH1[0-3] || 4 B-GLD(t+1)
//   ph2: MFMA m0-3/h1 || read aH1[4-7] ; vmcnt(0) ; barrier  (t+1 published)
//   ph3: MFMA m4-7/h1 || read next-tile ph0 frags from bufn ;
//        lgkmcnt(8) ; barrier  (all buf(t) reads drained)
// Hazard proof:
//  - visibility: each wave's 8 GLDs for t+1 issue in ph0/ph1; its vmcnt(0) at
//    ph2-end drains them; barrier joins all waves. ph3's bufn reads follow.
//  - overwrite: GLD(t+2)->buf(t&1) issues at iter t+1 ph0, after iter t's
//    final barrier; all buf(t) reads were consumed by iter-t MFMAs (compiler
//    waits) and fenced by lgkmcnt(8) (ph3's 8 bufn reads are the newest 8).
//  - prologue: stage tile 0, vmcnt(0)+barrier, read ph0 frags.
// LDS swizzle (BK=64 rows = 8 x 16B units): stored unit = u ^ (row&7);
// read-side XOR folds to per-lane constant; GLOBAL source inverse-swizzled
// (both-sides rule). Measured: SQ_LDS_BANK_CONFLICT = 0.
// Plateau evidence (counter-verified): lockstep 2-phase 133, same-phase
// 8-phase ports 126/131, 1-wave/SIMD 32x32 131, fused A-cvt 200, 3-deep
// counted ring null, 256x128 2-blocks/CU 135-137 (+45% FETCH), 32x32 shape
// in this schedule 142 (opaque b128 bank interaction). Cycle model:
// iter 4270 cy vs MFMA 2483 cy/SIMD, LDS ~2816 cy/CU — jointly limited.
// ---------------------------------------------------------------------------
#define BM 256
#define BN 256
#define BK 64
#define NT (K_DIM / BK)   // 64

#define GLD(src, dst) \
    __builtin_amdgcn_global_load_lds( \
        (const __attribute__((address_space(1))) void*)(src), \
        (__attribute__((address_space(3))) void*)(dst), 16, 0, 0)

#define MFMA(a, b, c) __builtin_amdgcn_mfma_f32_16x16x32_bf16(a, b, c, 0, 0, 0)

__global__ __launch_bounds__(512, 2) void gemm_bt_kernel(const short* __restrict__ A,
                                                         const short* __restrict__ Wd,
                                                         float* __restrict__ C) {
    __shared__ short lds[2 * 32768];   // 2 bufs x (A 32KB | B 32KB) = 128 KB

    const int tid  = threadIdx.x;
    const int wave = tid >> 6;
    const int lane = tid & 63;

    // XCD-chunked swizzle: 256 blocks -> 8 XCDs, each a 4x8 block chunk
    const int bid = blockIdx.x;
    const int xcd = bid & 7;
    const int s   = bid >> 3;
    const int by  = (xcd >> 1) * 4 + (s >> 3);
    const int bx  = (xcd & 1) * 8 + (s & 7);

    const int rowBase = by * BM;
    const int colBase = bx * BN;

    const int wr = wave >> 2;                 // 0..1  (128-row half)
    const int wc = wave & 3;                  // 0..3  (64-col quarter)

    // ---- staging: thread covers rows (tid>>3)+c*64, stored unit tid&7 ----
    const int rA0 = tid >> 3;                 // 0..63
    const int uu  = (tid & 7) ^ (rA0 & 7);    // inverse-swizzled logical unit
    const int stOff = rA0 * 64 + (tid & 7) * 8;   // shorts; +c*4096
    const short* aSrcB = A  + (size_t)(rowBase + rA0) * K_DIM + uu * 8;
    const short* bSrcB = Wd + (size_t)(colBase + rA0) * K_DIM + uu * 8;

    // ---- fragment read offsets (shorts) ----
    const int l15 = lane & 15;
    const int l4  = lane >> 4;
    const int uk0 = ((l4 ^ (l15 & 7))) * 8;   // h=0 stored-unit offset
    const int uk1 = uk0 ^ 32;                 // h=1 (unit XOR 4)
    const int aRow = (wr * 128 + l15) * 64;           // + m*1024 + ukh
    const int bRow = 16384 + (wc * 64 + l15) * 64;    // + n*1024 + ukh

    f32x4 acc[8][4] = {};
    short8 aC[4], bC[4];      // ph0 operands (loop-carried, written at ph3)

    // ---- prologue: stage tile 0 into buf0, publish, read ph0 frags ----
#pragma unroll
    for (int c = 0; c < 4; ++c)
        GLD(aSrcB + c * (64 * K_DIM), &lds[c * 4096 + stOff]);
#pragma unroll
    for (int c = 0; c < 4; ++c)
        GLD(bSrcB + c * (64 * K_DIM), &lds[16384 + c * 4096 + stOff]);
    asm volatile("s_waitcnt vmcnt(0)" ::: "memory");
    __builtin_amdgcn_s_barrier();
#pragma unroll
    for (int m = 0; m < 4; ++m) aC[m] = *(const short8*)&lds[aRow + m * 1024 + uk0];
#pragma unroll
    for (int n = 0; n < 4; ++n) bC[n] = *(const short8*)&lds[bRow + n * 1024 + uk0];

    for (int t = 0; t < NT; ++t) {
        const int buf  = (t & 1) * 32768;
        const int bufn = buf ^ 32768;
        const size_t kpre = (size_t)(((t + 1 < NT) ? (t + 1) : (NT - 1)) * BK);

        // ---- ph0: MFMA m0-3 x h0 ; read aH0[4-7] ; issue 4 A-GLD(t+1) ----
        short8 a1h0[4];
#pragma unroll
        for (int m = 0; m < 4; ++m)
            a1h0[m] = *(const short8*)&lds[buf + aRow + (m + 4) * 1024 + uk0];
#pragma unroll
        for (int c = 0; c < 4; ++c)
            GLD(aSrcB + kpre + c * (64 * K_DIM), &lds[bufn + c * 4096 + stOff]);
        __builtin_amdgcn_s_setprio(1);
#pragma unroll
        for (int m = 0; m < 4; ++m)
#pragma unroll
            for (int n = 0; n < 4; ++n)
                acc[m][n] = MFMA(aC[m], bC[n], acc[m][n]);
        __builtin_amdgcn_s_setprio(0);

        // ---- ph1: MFMA m4-7 x h0 ; read aH1[0-3], bH1[0-3] ; 4 B-GLD ----
        short8 a0h1[4], b1[4];
#pragma unroll
        for (int m = 0; m < 4; ++m)
            a0h1[m] = *(const short8*)&lds[buf + aRow + m * 1024 + uk1];
#pragma unroll
        for (int n = 0; n < 4; ++n)
            b1[n] = *(const short8*)&lds[buf + bRow + n * 1024 + uk1];
#pragma unroll
        for (int c = 0; c < 4; ++c)
            GLD(bSrcB + kpre + c * (64 * K_DIM), &lds[bufn + 16384 + c * 4096 + stOff]);
        __builtin_amdgcn_s_setprio(1);
#pragma unroll
        for (int m = 0; m < 4; ++m)
#pragma unroll
            for (int n = 0; n < 4; ++n)
                acc[m + 4][n] = MFMA(a1h0[m], bC[n], acc[m + 4][n]);
        __builtin_amdgcn_s_setprio(0);

        // ---- ph2: MFMA m0-3 x h1 ; read aH1[4-7] ; vmcnt(0)+barrier ----
        short8 a1h1[4];
#pragma unroll
        for (int m = 0; m < 4; ++m)
            a1h1[m] = *(const short8*)&lds[buf + aRow + (m + 4) * 1024 + uk1];
        __builtin_amdgcn_s_setprio(1);
#pragma unroll
        for (int m = 0; m < 4; ++m)
#pragma unroll
            for (int n = 0; n < 4; ++n)
                acc[m][n] = MFMA(a0h1[m], b1[n], acc[m][n]);
        __builtin_amdgcn_s_setprio(0);
        asm volatile("s_waitcnt vmcnt(0)" ::: "memory");   // tile t+1 landed
        __builtin_amdgcn_s_barrier();

        // ---- ph3: MFMA m4-7 x h1 ; read next-tile ph0 frags from bufn ----
#pragma unroll
        for (int m = 0; m < 4; ++m)
            aC[m] = *(const short8*)&lds[bufn + aRow + m * 1024 + uk0];
#pragma unroll
        for (int n = 0; n < 4; ++n)
            bC[n] = *(const short8*)&lds[bufn + bRow + n * 1024 + uk0];
        __builtin_amdgcn_s_setprio(1);
#pragma unroll
        for (int m = 0; m < 4; ++m)
#pragma unroll
            for (int n = 0; n < 4; ++n)
                acc[m + 4][n] = MFMA(a1h1[m], b1[n], acc[m + 4][n]);
        __builtin_amdgcn_s_setprio(0);
        asm volatile("s_waitcnt lgkmcnt(8)" ::: "memory"); // buf(t) reads drained
        __builtin_amdgcn_s_barrier();
    }

    // epilogue: C/D layout col = lane&15, row = (lane>>4)*4 + reg
    const int r0 = rowBase + wr * 128 + l4 * 4;
    const int c0 = colBase + wc * 64 + l15;
#pragma unroll
    for (int m = 0; m < 8; ++m)
#pragma unroll
        for (int n = 0; n < 4; ++n) {
            float* cp = C + (size_t)(r0 + m * 16) * M_DIM + (c0 + n * 16);
#pragma unroll
            for (int reg = 0; reg < 4; ++reg)
                cp[(size_t)reg * M_DIM] = acc[m][n][reg];
        }
}

// ---------------------------------------------------------------------------
extern "C" void kernel_launch(void* const* d_in, const int* in_sizes, int n_in,
                              void* d_out, int out_size, void* d_ws, size_t ws_size,
                              hipStream_t stream) {
    const float* inp  = (const float*)d_in[0];
    const int*   qidx = (const int*)d_in[1];
    const float* cb   = (const float*)d_in[2];
    float* out = (float*)d_out;

    short* Wb = (short*)d_ws;
    short* Ab = Wb + (size_t)M_DIM * K_DIM;

    prep_kernel<<<16384, 256, 0, stream>>>(qidx, cb, Wb, inp, Ab);

    gemm_bt_kernel<<<256, 512, 0, stream>>>(Ab, Wb, out);
}